// Round 2
// baseline (378.663 us; speedup 1.0000x reference)
//
#include <hip/hip_runtime.h>
#include <hip/hip_bf16.h>

// ColBERT MaxSim: B=64, SQ=128, SD=1024, H=768, D=128
#define NB 64
#define SQL 128
#define SDL 1024
#define HH 768
#define DD 128

typedef __attribute__((ext_vector_type(8))) short short8;
typedef __attribute__((ext_vector_type(4))) float f32x4;

__device__ __forceinline__ unsigned short bf16r(float f) {
    unsigned int u = __builtin_bit_cast(unsigned int, f);
    u += 0x7FFFu + ((u >> 16) & 1u);
    return (unsigned short)(u >> 16);
}

// ---------------- kernel 1: W fp32 -> bf16 (98304 elems) ----------------
__global__ __launch_bounds__(256) void k_wconv(const float* __restrict__ W,
                                               unsigned short* __restrict__ Wb) {
    int i = blockIdx.x * 256 + threadIdx.x;  // one float4 per thread, grid exact
    float4 v = reinterpret_cast<const float4*>(W)[i];
    ushort4 o;
    o.x = bf16r(v.x); o.y = bf16r(v.y); o.z = bf16r(v.z); o.w = bf16r(v.w);
    reinterpret_cast<ushort4*>(Wb)[i] = o;
}

// ---------------- kernel 2: project + L2-normalize ----------------
// Swapped-operand MFMA: D = W_tile(16d x 32k) * hidden_tile(32k x 16tok)
// C layout: col (lane&15) = token, row ((lane>>4)*4+reg) = d within tile.
// Each block: 128 tokens of one segment (query seg or one of 8 doc segs).
// Each wave: 32 tokens (2 n-tiles) x all 128 d (8 m-tiles).
__global__ __launch_bounds__(256) void k_project(
        const float* __restrict__ qh, const int* __restrict__ qm,
        const float* __restrict__ dh, const int* __restrict__ dm,
        const unsigned short* __restrict__ Wb,
        unsigned short* __restrict__ qe, unsigned short* __restrict__ de) {
    int bx = blockIdx.x;
    int b = bx / 9;
    int seg = bx % 9;
    const float* src;
    const int* mask;
    unsigned short* dst;
    if (seg == 0) {
        src = qh + (size_t)b * SQL * HH;
        mask = qm + (size_t)b * SQL;
        dst = qe + (size_t)b * SQL * DD;
    } else {
        size_t off = (size_t)(seg - 1) * 128;
        src = dh + ((size_t)b * SDL + off) * HH;
        mask = dm + (size_t)b * SDL + off;
        dst = de + ((size_t)b * SDL + off) * DD;
    }

    int lane = threadIdx.x & 63;
    int w = threadIdx.x >> 6;
    int l15 = lane & 15;
    int lg = lane >> 4;

    f32x4 acc[8][2];
#pragma unroll
    for (int dt = 0; dt < 8; ++dt)
#pragma unroll
        for (int jt = 0; jt < 2; ++jt) acc[dt][jt] = (f32x4){0.f, 0.f, 0.f, 0.f};

    const float* rowp0 = src + (size_t)(w * 32 + l15) * HH;
    const float* rowp1 = src + (size_t)(w * 32 + 16 + l15) * HH;

    for (int ks = 0; ks < HH / 32; ++ks) {
        int k0 = ks * 32 + lg * 8;
        short8 hf[2];
        {
            float4 a0 = *reinterpret_cast<const float4*>(rowp0 + k0);
            float4 a1 = *reinterpret_cast<const float4*>(rowp0 + k0 + 4);
            short8 s;
            s[0] = (short)bf16r(a0.x); s[1] = (short)bf16r(a0.y);
            s[2] = (short)bf16r(a0.z); s[3] = (short)bf16r(a0.w);
            s[4] = (short)bf16r(a1.x); s[5] = (short)bf16r(a1.y);
            s[6] = (short)bf16r(a1.z); s[7] = (short)bf16r(a1.w);
            hf[0] = s;
        }
        {
            float4 a0 = *reinterpret_cast<const float4*>(rowp1 + k0);
            float4 a1 = *reinterpret_cast<const float4*>(rowp1 + k0 + 4);
            short8 s;
            s[0] = (short)bf16r(a0.x); s[1] = (short)bf16r(a0.y);
            s[2] = (short)bf16r(a0.z); s[3] = (short)bf16r(a0.w);
            s[4] = (short)bf16r(a1.x); s[5] = (short)bf16r(a1.y);
            s[6] = (short)bf16r(a1.z); s[7] = (short)bf16r(a1.w);
            hf[1] = s;
        }
#pragma unroll
        for (int dt = 0; dt < 8; ++dt) {
            short8 wf = *reinterpret_cast<const short8*>(Wb + (size_t)(dt * 16 + l15) * HH + k0);
            acc[dt][0] = __builtin_amdgcn_mfma_f32_16x16x32_bf16(wf, hf[0], acc[dt][0], 0, 0, 0);
            acc[dt][1] = __builtin_amdgcn_mfma_f32_16x16x32_bf16(wf, hf[1], acc[dt][1], 0, 0, 0);
        }
    }

    // normalize per token + store bf16
#pragma unroll
    for (int jt = 0; jt < 2; ++jt) {
        float ss = 0.f;
#pragma unroll
        for (int dt = 0; dt < 8; ++dt) {
            ss += acc[dt][jt][0] * acc[dt][jt][0];
            ss += acc[dt][jt][1] * acc[dt][jt][1];
            ss += acc[dt][jt][2] * acc[dt][jt][2];
            ss += acc[dt][jt][3] * acc[dt][jt][3];
        }
        ss += __shfl_xor(ss, 16, 64);
        ss += __shfl_xor(ss, 32, 64);
        int tokl = w * 32 + jt * 16 + l15;
        int mk = mask[tokl];
        float scale = mk ? (1.0f / fmaxf(sqrtf(ss), 1e-12f)) : 0.0f;
        unsigned short* orow = dst + (size_t)tokl * DD + lg * 4;
#pragma unroll
        for (int dt = 0; dt < 8; ++dt) {
            ushort4 o;
            o.x = bf16r(acc[dt][jt][0] * scale);
            o.y = bf16r(acc[dt][jt][1] * scale);
            o.z = bf16r(acc[dt][jt][2] * scale);
            o.w = bf16r(acc[dt][jt][3] * scale);
            *reinterpret_cast<ushort4*>(orow + dt * 16) = o;
        }
    }
}

// ---------------- kernel 3: sim + running rowmax per 256-doc chunk ----------------
// grid (64 batches x 4 chunks); block 256 thr = 4 waves.
// LDS: q[128][128]bf16 (32KB) + doc[256][128]bf16 (64KB), XOR-swizzled 16B chunks.
__global__ __launch_bounds__(256) void k_sim(const unsigned short* __restrict__ qe,
                                             const unsigned short* __restrict__ de,
                                             float* __restrict__ partial) {
    __shared__ uint4 qs[SQL * 16];
    __shared__ uint4 dsm[256 * 16];
    __shared__ float bm[4][SQL];

    int b = blockIdx.x >> 2;
    int c = blockIdx.x & 3;

    const uint4* qg = reinterpret_cast<const uint4*>(qe + (size_t)b * SQL * DD);
    for (int idx = threadIdx.x; idx < SQL * 16; idx += 256) {
        int row = idx >> 4, ch = idx & 15;
        qs[row * 16 + (ch ^ (row & 7))] = qg[idx];
    }
    const uint4* dg = reinterpret_cast<const uint4*>(de + ((size_t)b * SDL + (size_t)c * 256) * DD);
    for (int idx = threadIdx.x; idx < 256 * 16; idx += 256) {
        int row = idx >> 4, ch = idx & 15;
        dsm[row * 16 + (ch ^ (row & 7))] = dg[idx];
    }
    __syncthreads();

    int lane = threadIdx.x & 63;
    int w = threadIdx.x >> 6;
    int l15 = lane & 15;
    int lg = lane >> 4;

    float rmax[8][4];
#pragma unroll
    for (int i = 0; i < 8; ++i)
#pragma unroll
        for (int r = 0; r < 4; ++r) rmax[i][r] = -3.4e38f;

    for (int i = 0; i < 8; ++i) {
        short8 a[4];
        int arow = i * 16 + l15;
#pragma unroll
        for (int ks = 0; ks < 4; ++ks) {
            int ch = ks * 4 + lg;
            a[ks] = *reinterpret_cast<const short8*>(&qs[arow * 16 + (ch ^ (arow & 7))]);
        }
#pragma unroll
        for (int jj = 0; jj < 4; ++jj) {
            int drow = (w * 4 + jj) * 16 + l15;
            f32x4 accv = (f32x4){0.f, 0.f, 0.f, 0.f};
#pragma unroll
            for (int ks = 0; ks < 4; ++ks) {
                int ch = ks * 4 + lg;
                short8 bf = *reinterpret_cast<const short8*>(&dsm[drow * 16 + (ch ^ (drow & 7))]);
                accv = __builtin_amdgcn_mfma_f32_16x16x32_bf16(a[ks], bf, accv, 0, 0, 0);
            }
#pragma unroll
            for (int r = 0; r < 4; ++r) rmax[i][r] = fmaxf(rmax[i][r], accv[r]);
        }
    }

    // reduce max over the 16 doc-columns held across lanes (xor 1,2,4,8)
#pragma unroll
    for (int i = 0; i < 8; ++i) {
#pragma unroll
        for (int r = 0; r < 4; ++r) {
            float v = rmax[i][r];
            v = fmaxf(v, __shfl_xor(v, 1, 64));
            v = fmaxf(v, __shfl_xor(v, 2, 64));
            v = fmaxf(v, __shfl_xor(v, 4, 64));
            v = fmaxf(v, __shfl_xor(v, 8, 64));
            if (l15 == 0) bm[w][i * 16 + lg * 4 + r] = v;
        }
    }
    __syncthreads();

    if (threadIdx.x < SQL) {
        int sq = threadIdx.x;
        float m = fmaxf(fmaxf(bm[0][sq], bm[1][sq]), fmaxf(bm[2][sq], bm[3][sq]));
        partial[((size_t)b * 4 + c) * SQL + sq] = m;
    }
}

// ---------------- kernel 4: max over chunks, sum over sq ----------------
__global__ __launch_bounds__(128) void k_reduce(const float* __restrict__ partial,
                                                float* __restrict__ out) {
    int b = blockIdx.x;
    int sq = threadIdx.x;  // 128 threads
    const float* p = partial + (size_t)b * 4 * SQL;
    float m = fmaxf(fmaxf(p[sq], p[SQL + sq]), fmaxf(p[2 * SQL + sq], p[3 * SQL + sq]));
    float s = m;
    s += __shfl_xor(s, 1, 64);
    s += __shfl_xor(s, 2, 64);
    s += __shfl_xor(s, 4, 64);
    s += __shfl_xor(s, 8, 64);
    s += __shfl_xor(s, 16, 64);
    s += __shfl_xor(s, 32, 64);
    __shared__ float tmp[2];
    int lane = threadIdx.x & 63;
    int wv = threadIdx.x >> 6;
    if (lane == 0) tmp[wv] = s;
    __syncthreads();
    if (threadIdx.x == 0) out[b] = tmp[0] + tmp[1];
}

extern "C" void kernel_launch(void* const* d_in, const int* in_sizes, int n_in,
                              void* d_out, int out_size, void* d_ws, size_t ws_size,
                              hipStream_t stream) {
    const float* qh = (const float*)d_in[0];
    const int* qm = (const int*)d_in[1];
    const float* dh = (const float*)d_in[2];
    const int* dm = (const int*)d_in[3];
    const float* W = (const float*)d_in[4];
    float* out = (float*)d_out;

    char* ws = (char*)d_ws;
    // layout: Wb [0,196608) | qe [196608, 2293760) | de [2293760, 19070976) | partial [19070976, 19202048)
    unsigned short* Wb = (unsigned short*)(ws);
    unsigned short* qe = (unsigned short*)(ws + 196608);
    unsigned short* de = (unsigned short*)(ws + 2293760);
    float* partial = (float*)(ws + 19070976);

    hipLaunchKernelGGL(k_wconv, dim3(96), dim3(256), 0, stream, W, Wb);
    hipLaunchKernelGGL(k_project, dim3(NB * 9), dim3(256), 0, stream,
                       qh, qm, dh, dm, Wb, qe, de);
    hipLaunchKernelGGL(k_sim, dim3(NB * 4), dim3(256), 0, stream, qe, de, partial);
    hipLaunchKernelGGL(k_reduce, dim3(NB), dim3(128), 0, stream, partial, out);
}